// Round 11
// baseline (118.260 us; speedup 1.0000x reference)
//
#include <hip/hip_runtime.h>
#include <math.h>

// Problem constants
#define HH 72
#define WW 96
#define NN (HH * WW)          // 6912
#define BB 2
#define CC 16
#define EPSF 1e-8f

// exp2 formulation: k = exp(-sq/0.1) = 2^(-sq * log2(e)/0.1)
#define S0  14.426950408889634f   // log2(e)/0.1
#define SCL 28.853900817779268f   // 2*S0

// tiling (R6/R10-proven configuration)
#define NTILES (NN / 16)          // 432 tiles of 16 points per batch
#define IT 4                      // i-tiles in registers per wave
#define WPB 4                     // waves per block
#define NIGQ (NTILES / (IT * WPB))    // 27 i-quads (16 i-tiles per block)
#define NJC 54                    // j-chunks
#define JT_PER_CHUNK (NTILES / NJC)   // 8 j-tiles per chunk
#define PAIRBLOCKS (BB * NIGQ * NJC)  // 2916
#define PB_PER_B (PAIRBLOCKS / BB)    // 1458
#define PREPBLOCKS (BB * NTILES / 4)  // 216
#define PREP_PER_B (PREPBLOCKS / BB)  // 108

// workspace: 5 fragment arrays (shorts), each [BB*NTILES][64 lanes][8 bf16]
// B arrays (BG,BT,BN) CONTIGUOUS so pair waves 0..2 stage by wave id.
#define FRAG_ELEMS ((size_t)BB * NTILES * 64 * 8)
#define AGRAM_OFF ((size_t)0)
#define AARGS_OFF (1 * FRAG_ELEMS)
#define BG_OFF    (2 * FRAG_ELEMS)
#define BT_OFF    (3 * FRAG_ELEMS)
#define BN_OFF    (4 * FRAG_ELEMS)
#define FRAG_TOTAL (5 * FRAG_ELEMS)                // shorts
#define PART_FOFF (FRAG_TOTAL / 2)                 // floats: 2916 block partials
#define SRED_FOFF (PART_FOFF + PAIRBLOCKS)         // 216*3 prep partials

typedef __attribute__((ext_vector_type(8))) short s8v;
typedef __attribute__((ext_vector_type(4))) float f4v;

#if __has_builtin(__builtin_amdgcn_exp2f)
#define EXP2(x) __builtin_amdgcn_exp2f(x)
#else
#define EXP2(x) exp2f(x)
#endif

// software exp2 on the MAIN VALU pipe (trans pipe stays free):
// rndne + sub + 5 fma + cvt + ldexp = 9 VALU instrs, rel err ~1e-6.
// Handles large-negative args via v_ldexp underflow -> 0.
__device__ __forceinline__ float fexp2(float x) {
    float n = rintf(x);
    float f = x - n;                 // f in [-0.5, 0.5]
    float p = 1.3697664e-3f;
    p = fmaf(p, f, 9.6178371e-3f);
    p = fmaf(p, f, 5.5502045e-2f);
    p = fmaf(p, f, 2.4022652e-1f);
    p = fmaf(p, f, 6.9314718e-1f);
    p = fmaf(p, f, 1.0f);
    return __builtin_ldexpf(p, (int)n);
}

__device__ __forceinline__ unsigned short f2bf(float f) {
    unsigned u = __builtin_bit_cast(unsigned, f);
    unsigned r = (u + 0x7FFFu + ((u >> 16) & 1u)) >> 16;   // RNE
    return (unsigned short)r;
}
__device__ __forceinline__ float bf2f(unsigned short s) {
    unsigned u = ((unsigned)s) << 16;
    return __builtin_bit_cast(float, u);
}

// prep: one wave per 16-point tile; lane = q*16 + m matches fragment layout,
// so every fragment store is a lane-consecutive 16B write.
__global__ __launch_bounds__(256) void prep_kernel(const float* __restrict__ f1,
                                                   const float* __restrict__ f2,
                                                   const float* __restrict__ d1,
                                                   const float* __restrict__ d2,
                                                   const float* __restrict__ pose,
                                                   const float* __restrict__ yz1,
                                                   short* __restrict__ frag,
                                                   float* __restrict__ sred) {
    int lane = threadIdx.x & 63;
    int q = lane >> 4, m = lane & 15;
    int tileg = blockIdx.x * 4 + (threadIdx.x >> 6);   // global tile in [0, BB*NTILES)
    int b = tileg / NTILES;
    int tile = tileg - b * NTILES;
    int n = tile * 16 + m;
    int idx = b * NN + n;

    // load this thread's 8 channels of f1 and f2
    int c0 = (q & 1) * 8;
    const float* f1b = f1 + (size_t)b * CC * NN + (size_t)c0 * NN + n;
    const float* f2b = f2 + (size_t)b * CC * NN + (size_t)c0 * NN + n;
    float v1[8], v2[8];
    float s1p = 0.f, s2p = 0.f;
#pragma unroll
    for (int j = 0; j < 8; j++) { v1[j] = f1b[(size_t)j * NN]; s1p += v1[j] * v1[j]; }
#pragma unroll
    for (int j = 0; j < 8; j++) { v2[j] = f2b[(size_t)j * NN]; s2p += v2[j] * v2[j]; }
    float s1 = s1p + __shfl_xor(s1p, 16, 64);   // quad pairs (0,1),(2,3) hold ch 0-7 / 8-15
    float s2 = s2p + __shfl_xor(s2p, 16, 64);
    float n1 = sqrtf(s1), n2 = sqrtf(s2);
    float dd1 = d1[idx], dd2 = d2[idx];
    float m1 = dd1 > 0.f ? 1.f : 0.f;
    float m2 = dd2 > 0.f ? 1.f : 0.f;
    float inv1 = m1 / (n1 + EPSF);
    float inv2 = m2 / (n2 + EPSF);

    bool isLoHalf = (q >= 2);   // A-gram: [f1h(16) | f1l(16)]
    s8v ga, gb;
#pragma unroll
    for (int j = 0; j < 8; j++) {
        float x1 = v1[j] * inv1;
        unsigned short h1 = f2bf(x1);
        unsigned short l1 = f2bf(x1 - bf2f(h1));
        ga[j] = (short)(isLoHalf ? l1 : h1);
        gb[j] = (short)f2bf(v2[j] * inv2);       // B-gram: [f2h | f2h] (lo dropped)
    }

    // geometry (computed redundantly per quad; cheap)
    float y0 = yz1[n], y1 = yz1[NN + n], y2 = yz1[2 * NN + n];
    float x1x = y0 * dd1, x1y = y1 * dd1, x1z = y2 * dd1;
    float x2x = y0 * dd2, x2y = y1 * dd2, x2z = y2 * dd2;
    const float* P = pose + b * 16;
    float tx = P[0] * x2x + P[1] * x2y + P[2] * x2z + P[3];
    float ty = P[4] * x2x + P[5] * x2y + P[6] * x2z + P[7];
    float tz = P[8] * x2x + P[9] * x2y + P[10] * x2z + P[11];

    // K-slot layout for args: k0-4 = uh.vh, k8-12 = ul.vh, k16-20 = uh.vl, rest 0
    float u[5]  = { SCL * x1x, SCL * x1y, SCL * x1z,
                    -S0 * (x1x * x1x + x1y * x1y + x1z * x1z), 1.f };
    float vt[5] = { tx, ty, tz, 1.f, -S0 * (tx * tx + ty * ty + tz * tz) };
    float vn[5] = { x2x, x2y, x2z, 1.f, -S0 * (x2x * x2x + x2y * x2y + x2z * x2z) };

    s8v av, btv, bnv;
#pragma unroll
    for (int k = 0; k < 5; k++) {
        unsigned short uh = f2bf(u[k]);
        unsigned short ul = f2bf(u[k] - bf2f(uh));
        unsigned short a = (q == 1) ? ul : uh;          // q0,q2 -> hi; q1 -> lo
        if (q == 3) a = 0;
        av[k] = (short)a;
        unsigned short vth = f2bf(vt[k]);
        unsigned short vtl = f2bf(vt[k] - bf2f(vth));
        unsigned short bt = (q == 2) ? vtl : vth;       // q0,q1 -> hi; q2 -> lo
        if (q == 3) bt = 0;
        btv[k] = (short)bt;
        unsigned short vnh = f2bf(vn[k]);
        unsigned short vnl = f2bf(vn[k] - bf2f(vnh));
        unsigned short bn = (q == 2) ? vnl : vnh;
        if (q == 3) bn = 0;
        bnv[k] = (short)bn;
    }
#pragma unroll
    for (int k = 5; k < 8; k++) { av[k] = 0; btv[k] = 0; bnv[k] = 0; }

    size_t off = ((size_t)tileg * 64 + lane) * 8;   // shorts
    *(s8v*)(frag + AGRAM_OFF + off) = ga;
    *(s8v*)(frag + AARGS_OFF + off) = av;
    *(s8v*)(frag + BG_OFF    + off) = gb;
    *(s8v*)(frag + BT_OFF    + off) = btv;
    *(s8v*)(frag + BN_OFF    + off) = bnv;

    // per-batch reductions (only q==0 lanes contribute; block lies in one batch)
    float lm1  = (q == 0) ? m1 : 0.f;
    float lm2  = (q == 0) ? m2 : 0.f;
    float lfns = (q == 0) ? (n1 * m1 + n2 * m2) : 0.f;
#pragma unroll
    for (int offr = 32; offr > 0; offr >>= 1) {
        lm1  += __shfl_down(lm1, offr, 64);
        lm2  += __shfl_down(lm2, offr, 64);
        lfns += __shfl_down(lfns, offr, 64);
    }
    __shared__ float red[3][4];
    int wv = threadIdx.x >> 6;
    if (lane == 0) { red[0][wv] = lm1; red[1][wv] = lm2; red[2][wv] = lfns; }
    __syncthreads();
    if (threadIdx.x == 0) {
        sred[blockIdx.x * 3 + 0] = red[0][0] + red[0][1] + red[0][2] + red[0][3];
        sred[blockIdx.x * 3 + 1] = red[1][0] + red[1][1] + red[1][2] + red[1][3];
        sred[blockIdx.x * 3 + 2] = red[2][0] + red[2][1] + red[2][2] + red[2][3];
    }
}

// pair: R10 structure; epilogue splits exp work across pipes —
// at-path uses v_exp_f32 (trans pipe), an-path uses software exp2 (main VALU).
// Separate accumulator sets decouple the two chains.
__global__ __launch_bounds__(256, 4) void pair_kernel(const short* __restrict__ frag,
                                                      float* __restrict__ part) {
    int tid = threadIdx.x;
    int lane = tid & 63;
    int w = tid >> 6;                 // wave id 0..3
    int blk = blockIdx.x;
    int b = blk / (NIGQ * NJC);
    int r = blk - b * (NIGQ * NJC);
    int igq = r / NJC;
    int jc = r - igq * NJC;

    // A fragments: wave w covers i-tiles igq*16 + w*4 .. +3
    const s8v* AG = (const s8v*)(frag + AGRAM_OFF);
    const s8v* AA = (const s8v*)(frag + AARGS_OFF);
    s8v ag[IT], aa[IT];
    int it0 = igq * (IT * WPB) + w * IT;
#pragma unroll
    for (int t = 0; t < IT; t++) {
        size_t ai = (size_t)(b * NTILES + it0 + t) * 64 + lane;
        ag[t] = AG[ai];
        aa[t] = AA[ai];
    }

    // B staging: arrays BG,BT,BN contiguous; wave w<3 stages array w.
    size_t tbase = (size_t)(b * NTILES + jc * JT_PER_CHUNK) * 64;   // s8v units
    const s8v* myArr = (const s8v*)(frag + BG_OFF) + (size_t)w * (FRAG_ELEMS / 8) + tbase;

    __shared__ s8v sB[2][3][64];      // [buf][array][lane] = 6 KB

    s8v gv;
    if (w < 3) {
        gv = myArr[lane];             // jt 0
        sB[0][w][lane] = gv;
    }
    __syncthreads();

    float a0 = 0.f, a1 = 0.f, a2 = 0.f, a3 = 0.f;   // at-path accumulators
    float b0 = 0.f, b1 = 0.f, b2 = 0.f, b3 = 0.f;   // an-path accumulators
    f4v z = { 0.f, 0.f, 0.f, 0.f };
#pragma unroll 1
    for (int jj = 0; jj < JT_PER_CHUNK; jj++) {
        int cur = jj & 1;
        if (w < 3 && jj + 1 < JT_PER_CHUNK)
            gv = myArr[(size_t)(jj + 1) * 64 + lane];   // prefetch next jt

        s8v bg = sB[cur][0][lane];
        s8v bt = sB[cur][1][lane];
        s8v bn = sB[cur][2][lane];
#pragma unroll
        for (int t = 0; t < IT; t++) {
            f4v g  = __builtin_amdgcn_mfma_f32_16x16x32_bf16(ag[t], bg, z, 0, 0, 0);
            f4v at = __builtin_amdgcn_mfma_f32_16x16x32_bf16(aa[t], bt, z, 0, 0, 0);
            f4v an = __builtin_amdgcn_mfma_f32_16x16x32_bf16(aa[t], bn, z, 0, 0, 0);
            a0 = fmaf(EXP2(at[0]), g[0], a0);
            a1 = fmaf(EXP2(at[1]), g[1], a1);
            a2 = fmaf(EXP2(at[2]), g[2], a2);
            a3 = fmaf(EXP2(at[3]), g[3], a3);
            b0 = fmaf(fexp2(an[0]), g[0], b0);
            b1 = fmaf(fexp2(an[1]), g[1], b1);
            b2 = fmaf(fexp2(an[2]), g[2], b2);
            b3 = fmaf(fexp2(an[3]), g[3], b3);
        }

        if (w < 3 && jj + 1 < JT_PER_CHUNK)
            sB[cur ^ 1][w][lane] = gv;   // stage next jt into the other buffer
        __syncthreads();
    }

    float loss = ((a0 + a1) + (a2 + a3)) - ((b0 + b1) + (b2 + b3));
#pragma unroll
    for (int off = 32; off > 0; off >>= 1) loss += __shfl_down(loss, off, 64);
    __shared__ float red[WPB];
    if (lane == 0) red[w] = loss;
    __syncthreads();
    if (tid == 0) part[blockIdx.x] = (red[0] + red[1]) + (red[2] + red[3]);
}

__global__ __launch_bounds__(256) void finalize_kernel(const float* __restrict__ wsF,
                                                       float* __restrict__ out) {
    int tid = threadIdx.x;
    __shared__ float red[BB][4];
    __shared__ float sS[BB][3][4];
#pragma unroll
    for (int b = 0; b < BB; b++) {
        float acc = 0.f;
        for (int k = tid; k < PB_PER_B; k += 256)
            acc += wsF[PART_FOFF + (size_t)b * PB_PER_B + k];
        float a1 = 0.f, a2 = 0.f, a3 = 0.f;
        for (int k = tid; k < PREP_PER_B; k += 256) {
            size_t o = SRED_FOFF + (size_t)(b * PREP_PER_B + k) * 3;
            a1 += wsF[o + 0]; a2 += wsF[o + 1]; a3 += wsF[o + 2];
        }
#pragma unroll
        for (int off = 32; off > 0; off >>= 1) {
            acc += __shfl_down(acc, off, 64);
            a1  += __shfl_down(a1, off, 64);
            a2  += __shfl_down(a2, off, 64);
            a3  += __shfl_down(a3, off, 64);
        }
        int lane = tid & 63, wv = tid >> 6;
        if (lane == 0) {
            red[b][wv] = acc;
            sS[b][0][wv] = a1; sS[b][1][wv] = a2; sS[b][2][wv] = a3;
        }
    }
    __syncthreads();
    if (tid == 0) {
        float tot = 0.f, fns = 0.f;
        for (int b = 0; b < BB; b++) {
            float raw = red[b][0] + red[b][1] + red[b][2] + red[b][3];
            float S1 = sS[b][0][0] + sS[b][0][1] + sS[b][0][2] + sS[b][0][3];
            float S2 = sS[b][1][0] + sS[b][1][1] + sS[b][1][2] + sS[b][1][3];
            fns += sS[b][2][0] + sS[b][2][1] + sS[b][2][2] + sS[b][2][3];
            tot += -raw / (S1 * S2);
        }
        out[0] = tot;    // final_loss
        out[1] = tot;    // inner_neg
        out[2] = 100.f * fns;
    }
}

extern "C" void kernel_launch(void* const* d_in, const int* in_sizes, int n_in,
                              void* d_out, int out_size, void* d_ws, size_t ws_size,
                              hipStream_t stream) {
    const float* f1   = (const float*)d_in[0];
    const float* f2   = (const float*)d_in[1];
    const float* d1   = (const float*)d_in[2];
    const float* d2   = (const float*)d_in[3];
    const float* pose = (const float*)d_in[4];
    const float* yz1  = (const float*)d_in[7];
    short* frag = (short*)d_ws;
    float* wsF  = (float*)d_ws;
    float* out  = (float*)d_out;

    prep_kernel<<<PREPBLOCKS, 256, 0, stream>>>(f1, f2, d1, d2, pose, yz1,
                                                frag, wsF + SRED_FOFF);
    pair_kernel<<<PAIRBLOCKS, 256, 0, stream>>>(frag, wsF + PART_FOFF);
    finalize_kernel<<<1, 256, 0, stream>>>(wsF, out);
}

// Round 12
// 102.723 us; speedup vs baseline: 1.1512x; 1.1512x over previous
//
#include <hip/hip_runtime.h>
#include <math.h>

// Problem constants
#define HH 72
#define WW 96
#define NN (HH * WW)          // 6912
#define BB 2
#define CC 16
#define EPSF 1e-8f

// exp2 formulation: k = exp(-sq/0.1) = 2^(-sq * log2(e)/0.1)
#define S0  14.426950408889634f   // log2(e)/0.1
#define SCL 28.853900817779268f   // 2*S0

// tiling (R6/R10-proven configuration — best measured: 102.8 µs total)
#define NTILES (NN / 16)          // 432 tiles of 16 points per batch
#define IT 4                      // i-tiles in registers per wave
#define WPB 4                     // waves per block
#define NIGQ (NTILES / (IT * WPB))    // 27 i-quads (16 i-tiles per block)
#define NJC 54                    // j-chunks
#define JT_PER_CHUNK (NTILES / NJC)   // 8 j-tiles per chunk
#define PAIRBLOCKS (BB * NIGQ * NJC)  // 2916
#define PB_PER_B (PAIRBLOCKS / BB)    // 1458
#define PREPBLOCKS (BB * NTILES / 4)  // 216
#define PREP_PER_B (PREPBLOCKS / BB)  // 108

// workspace: 5 fragment arrays (shorts), each [BB*NTILES][64 lanes][8 bf16]
// B arrays (BG,BT,BN) CONTIGUOUS so pair waves 0..2 stage by wave id.
#define FRAG_ELEMS ((size_t)BB * NTILES * 64 * 8)
#define AGRAM_OFF ((size_t)0)
#define AARGS_OFF (1 * FRAG_ELEMS)
#define BG_OFF    (2 * FRAG_ELEMS)
#define BT_OFF    (3 * FRAG_ELEMS)
#define BN_OFF    (4 * FRAG_ELEMS)
#define FRAG_TOTAL (5 * FRAG_ELEMS)                // shorts
#define PART_FOFF (FRAG_TOTAL / 2)                 // floats: 2916 block partials
#define SRED_FOFF (PART_FOFF + PAIRBLOCKS)         // 216*3 prep partials

typedef __attribute__((ext_vector_type(8))) short s8v;
typedef __attribute__((ext_vector_type(4))) float f4v;

#if __has_builtin(__builtin_amdgcn_exp2f)
#define EXP2(x) __builtin_amdgcn_exp2f(x)
#else
#define EXP2(x) exp2f(x)
#endif

__device__ __forceinline__ unsigned short f2bf(float f) {
    unsigned u = __builtin_bit_cast(unsigned, f);
    unsigned r = (u + 0x7FFFu + ((u >> 16) & 1u)) >> 16;   // RNE
    return (unsigned short)r;
}
__device__ __forceinline__ float bf2f(unsigned short s) {
    unsigned u = ((unsigned)s) << 16;
    return __builtin_bit_cast(float, u);
}

// prep: one wave per 16-point tile; lane = q*16 + m matches fragment layout,
// so every fragment store is a lane-consecutive 16B write.
__global__ __launch_bounds__(256) void prep_kernel(const float* __restrict__ f1,
                                                   const float* __restrict__ f2,
                                                   const float* __restrict__ d1,
                                                   const float* __restrict__ d2,
                                                   const float* __restrict__ pose,
                                                   const float* __restrict__ yz1,
                                                   short* __restrict__ frag,
                                                   float* __restrict__ sred) {
    int lane = threadIdx.x & 63;
    int q = lane >> 4, m = lane & 15;
    int tileg = blockIdx.x * 4 + (threadIdx.x >> 6);   // global tile in [0, BB*NTILES)
    int b = tileg / NTILES;
    int tile = tileg - b * NTILES;
    int n = tile * 16 + m;
    int idx = b * NN + n;

    // load this thread's 8 channels of f1 and f2
    int c0 = (q & 1) * 8;
    const float* f1b = f1 + (size_t)b * CC * NN + (size_t)c0 * NN + n;
    const float* f2b = f2 + (size_t)b * CC * NN + (size_t)c0 * NN + n;
    float v1[8], v2[8];
    float s1p = 0.f, s2p = 0.f;
#pragma unroll
    for (int j = 0; j < 8; j++) { v1[j] = f1b[(size_t)j * NN]; s1p += v1[j] * v1[j]; }
#pragma unroll
    for (int j = 0; j < 8; j++) { v2[j] = f2b[(size_t)j * NN]; s2p += v2[j] * v2[j]; }
    float s1 = s1p + __shfl_xor(s1p, 16, 64);   // quad pairs (0,1),(2,3) hold ch 0-7 / 8-15
    float s2 = s2p + __shfl_xor(s2p, 16, 64);
    float n1 = sqrtf(s1), n2 = sqrtf(s2);
    float dd1 = d1[idx], dd2 = d2[idx];
    float m1 = dd1 > 0.f ? 1.f : 0.f;
    float m2 = dd2 > 0.f ? 1.f : 0.f;
    float inv1 = m1 / (n1 + EPSF);
    float inv2 = m2 / (n2 + EPSF);

    bool isLoHalf = (q >= 2);   // A-gram: [f1h(16) | f1l(16)]
    s8v ga, gb;
#pragma unroll
    for (int j = 0; j < 8; j++) {
        float x1 = v1[j] * inv1;
        unsigned short h1 = f2bf(x1);
        unsigned short l1 = f2bf(x1 - bf2f(h1));
        ga[j] = (short)(isLoHalf ? l1 : h1);
        gb[j] = (short)f2bf(v2[j] * inv2);       // B-gram: [f2h | f2h] (lo dropped)
    }

    // geometry (computed redundantly per quad; cheap)
    float y0 = yz1[n], y1 = yz1[NN + n], y2 = yz1[2 * NN + n];
    float x1x = y0 * dd1, x1y = y1 * dd1, x1z = y2 * dd1;
    float x2x = y0 * dd2, x2y = y1 * dd2, x2z = y2 * dd2;
    const float* P = pose + b * 16;
    float tx = P[0] * x2x + P[1] * x2y + P[2] * x2z + P[3];
    float ty = P[4] * x2x + P[5] * x2y + P[6] * x2z + P[7];
    float tz = P[8] * x2x + P[9] * x2y + P[10] * x2z + P[11];

    // K-slot layout for args: k0-4 = uh.vh, k8-12 = ul.vh, k16-20 = uh.vl, rest 0
    float u[5]  = { SCL * x1x, SCL * x1y, SCL * x1z,
                    -S0 * (x1x * x1x + x1y * x1y + x1z * x1z), 1.f };
    float vt[5] = { tx, ty, tz, 1.f, -S0 * (tx * tx + ty * ty + tz * tz) };
    float vn[5] = { x2x, x2y, x2z, 1.f, -S0 * (x2x * x2x + x2y * x2y + x2z * x2z) };

    s8v av, btv, bnv;
#pragma unroll
    for (int k = 0; k < 5; k++) {
        unsigned short uh = f2bf(u[k]);
        unsigned short ul = f2bf(u[k] - bf2f(uh));
        unsigned short a = (q == 1) ? ul : uh;          // q0,q2 -> hi; q1 -> lo
        if (q == 3) a = 0;
        av[k] = (short)a;
        unsigned short vth = f2bf(vt[k]);
        unsigned short vtl = f2bf(vt[k] - bf2f(vth));
        unsigned short bt = (q == 2) ? vtl : vth;       // q0,q1 -> hi; q2 -> lo
        if (q == 3) bt = 0;
        btv[k] = (short)bt;
        unsigned short vnh = f2bf(vn[k]);
        unsigned short vnl = f2bf(vn[k] - bf2f(vnh));
        unsigned short bn = (q == 2) ? vnl : vnh;
        if (q == 3) bn = 0;
        bnv[k] = (short)bn;
    }
#pragma unroll
    for (int k = 5; k < 8; k++) { av[k] = 0; btv[k] = 0; bnv[k] = 0; }

    size_t off = ((size_t)tileg * 64 + lane) * 8;   // shorts
    *(s8v*)(frag + AGRAM_OFF + off) = ga;
    *(s8v*)(frag + AARGS_OFF + off) = av;
    *(s8v*)(frag + BG_OFF    + off) = gb;
    *(s8v*)(frag + BT_OFF    + off) = btv;
    *(s8v*)(frag + BN_OFF    + off) = bnv;

    // per-batch reductions (only q==0 lanes contribute; block lies in one batch)
    float lm1  = (q == 0) ? m1 : 0.f;
    float lm2  = (q == 0) ? m2 : 0.f;
    float lfns = (q == 0) ? (n1 * m1 + n2 * m2) : 0.f;
#pragma unroll
    for (int offr = 32; offr > 0; offr >>= 1) {
        lm1  += __shfl_down(lm1, offr, 64);
        lm2  += __shfl_down(lm2, offr, 64);
        lfns += __shfl_down(lfns, offr, 64);
    }
    __shared__ float red[3][4];
    int wv = threadIdx.x >> 6;
    if (lane == 0) { red[0][wv] = lm1; red[1][wv] = lm2; red[2][wv] = lfns; }
    __syncthreads();
    if (threadIdx.x == 0) {
        sred[blockIdx.x * 3 + 0] = red[0][0] + red[0][1] + red[0][2] + red[0][3];
        sred[blockIdx.x * 3 + 1] = red[1][0] + red[1][1] + red[1][2] + red[1][3];
        sred[blockIdx.x * 3 + 2] = red[2][0] + red[2][1] + red[2][2] + red[2][3];
    }
}

// pair: R10 configuration (best measured). Per-jt double-buffered LDS staging
// (waves 0-2 stage arrays 0-2), minimal 16-instr epilogue per t-iter
// (8 v_exp_f32 single-issue + 4 sub + 4 fma), (256,4) to avoid spills.
__global__ __launch_bounds__(256, 4) void pair_kernel(const short* __restrict__ frag,
                                                      float* __restrict__ part) {
    int tid = threadIdx.x;
    int lane = tid & 63;
    int w = tid >> 6;                 // wave id 0..3
    int blk = blockIdx.x;
    int b = blk / (NIGQ * NJC);
    int r = blk - b * (NIGQ * NJC);
    int igq = r / NJC;
    int jc = r - igq * NJC;

    // A fragments: wave w covers i-tiles igq*16 + w*4 .. +3
    const s8v* AG = (const s8v*)(frag + AGRAM_OFF);
    const s8v* AA = (const s8v*)(frag + AARGS_OFF);
    s8v ag[IT], aa[IT];
    int it0 = igq * (IT * WPB) + w * IT;
#pragma unroll
    for (int t = 0; t < IT; t++) {
        size_t ai = (size_t)(b * NTILES + it0 + t) * 64 + lane;
        ag[t] = AG[ai];
        aa[t] = AA[ai];
    }

    // B staging: arrays BG,BT,BN contiguous; wave w<3 stages array w.
    size_t tbase = (size_t)(b * NTILES + jc * JT_PER_CHUNK) * 64;   // s8v units
    const s8v* myArr = (const s8v*)(frag + BG_OFF) + (size_t)w * (FRAG_ELEMS / 8) + tbase;

    __shared__ s8v sB[2][3][64];      // [buf][array][lane] = 6 KB

    s8v gv;
    if (w < 3) {
        gv = myArr[lane];             // jt 0
        sB[0][w][lane] = gv;
    }
    __syncthreads();

    float a0 = 0.f, a1 = 0.f, a2 = 0.f, a3 = 0.f;
    f4v z = { 0.f, 0.f, 0.f, 0.f };
#pragma unroll 1
    for (int jj = 0; jj < JT_PER_CHUNK; jj++) {
        int cur = jj & 1;
        if (w < 3 && jj + 1 < JT_PER_CHUNK)
            gv = myArr[(size_t)(jj + 1) * 64 + lane];   // prefetch next jt

        s8v bg = sB[cur][0][lane];
        s8v bt = sB[cur][1][lane];
        s8v bn = sB[cur][2][lane];
#pragma unroll
        for (int t = 0; t < IT; t++) {
            f4v g  = __builtin_amdgcn_mfma_f32_16x16x32_bf16(ag[t], bg, z, 0, 0, 0);
            f4v at = __builtin_amdgcn_mfma_f32_16x16x32_bf16(aa[t], bt, z, 0, 0, 0);
            f4v an = __builtin_amdgcn_mfma_f32_16x16x32_bf16(aa[t], bn, z, 0, 0, 0);
            a0 = fmaf(EXP2(at[0]) - EXP2(an[0]), g[0], a0);
            a1 = fmaf(EXP2(at[1]) - EXP2(an[1]), g[1], a1);
            a2 = fmaf(EXP2(at[2]) - EXP2(an[2]), g[2], a2);
            a3 = fmaf(EXP2(at[3]) - EXP2(an[3]), g[3], a3);
        }

        if (w < 3 && jj + 1 < JT_PER_CHUNK)
            sB[cur ^ 1][w][lane] = gv;   // stage next jt into the other buffer
        __syncthreads();
    }

    float loss = (a0 + a1) + (a2 + a3);
#pragma unroll
    for (int off = 32; off > 0; off >>= 1) loss += __shfl_down(loss, off, 64);
    __shared__ float red[WPB];
    if (lane == 0) red[w] = loss;
    __syncthreads();
    if (tid == 0) part[blockIdx.x] = (red[0] + red[1]) + (red[2] + red[3]);
}

__global__ __launch_bounds__(256) void finalize_kernel(const float* __restrict__ wsF,
                                                       float* __restrict__ out) {
    int tid = threadIdx.x;
    __shared__ float red[BB][4];
    __shared__ float sS[BB][3][4];
#pragma unroll
    for (int b = 0; b < BB; b++) {
        float acc = 0.f;
        for (int k = tid; k < PB_PER_B; k += 256)
            acc += wsF[PART_FOFF + (size_t)b * PB_PER_B + k];
        float a1 = 0.f, a2 = 0.f, a3 = 0.f;
        for (int k = tid; k < PREP_PER_B; k += 256) {
            size_t o = SRED_FOFF + (size_t)(b * PREP_PER_B + k) * 3;
            a1 += wsF[o + 0]; a2 += wsF[o + 1]; a3 += wsF[o + 2];
        }
#pragma unroll
        for (int off = 32; off > 0; off >>= 1) {
            acc += __shfl_down(acc, off, 64);
            a1  += __shfl_down(a1, off, 64);
            a2  += __shfl_down(a2, off, 64);
            a3  += __shfl_down(a3, off, 64);
        }
        int lane = tid & 63, wv = tid >> 6;
        if (lane == 0) {
            red[b][wv] = acc;
            sS[b][0][wv] = a1; sS[b][1][wv] = a2; sS[b][2][wv] = a3;
        }
    }
    __syncthreads();
    if (tid == 0) {
        float tot = 0.f, fns = 0.f;
        for (int b = 0; b < BB; b++) {
            float raw = red[b][0] + red[b][1] + red[b][2] + red[b][3];
            float S1 = sS[b][0][0] + sS[b][0][1] + sS[b][0][2] + sS[b][0][3];
            float S2 = sS[b][1][0] + sS[b][1][1] + sS[b][1][2] + sS[b][1][3];
            fns += sS[b][2][0] + sS[b][2][1] + sS[b][2][2] + sS[b][2][3];
            tot += -raw / (S1 * S2);
        }
        out[0] = tot;    // final_loss
        out[1] = tot;    // inner_neg
        out[2] = 100.f * fns;
    }
}

extern "C" void kernel_launch(void* const* d_in, const int* in_sizes, int n_in,
                              void* d_out, int out_size, void* d_ws, size_t ws_size,
                              hipStream_t stream) {
    const float* f1   = (const float*)d_in[0];
    const float* f2   = (const float*)d_in[1];
    const float* d1   = (const float*)d_in[2];
    const float* d2   = (const float*)d_in[3];
    const float* pose = (const float*)d_in[4];
    const float* yz1  = (const float*)d_in[7];
    short* frag = (short*)d_ws;
    float* wsF  = (float*)d_ws;
    float* out  = (float*)d_out;

    prep_kernel<<<PREPBLOCKS, 256, 0, stream>>>(f1, f2, d1, d2, pose, yz1,
                                                frag, wsF + SRED_FOFF);
    pair_kernel<<<PAIRBLOCKS, 256, 0, stream>>>(frag, wsF + PART_FOFF);
    finalize_kernel<<<1, 256, 0, stream>>>(wsF, out);
}